// Round 8
// baseline (68.361 us; speedup 1.0000x reference)
//
#include <hip/hip_runtime.h>

// CRF-RNN mean-field, 2 iterations, N=8192 (32x16x16), C=4.
// Spatial attention: exactly separable (regular-grid Gaussian) -> 3 dense 1-D convs.
// Bilateral attention: N^2, compile-time split-K (KS) over j.
// Dispatches: prep | fused(conv+bilat) | reduce_finish(+softmax) | fused | reduce_finish.
// All per-voxel features (pos/theta, rgb/theta, -0.5|f|^2) and softmax(q) are
// precomputed once per dispatch-chain; bilat blocks only load float4s.

#define HH 32
#define WW 16
#define DDD 16
#define NN (HH * WW * DDD)    // 8192
#define KS 128                // split-K over j (compile-time)
#define JC (NN / KS)          // 64 j per block
#define CONVB 32              // conv blocks come FIRST in the fused grid
#define GB 2048               // bilat blocks (16 i-tiles x KS)
#define L2E 1.4426950408889634f
#define C18 (L2E / 18.0f)     // exp(-d^2/(2*3^2)) == exp2(-d^2*C18)
#define SQL2E 1.2011224087864498f   // sqrt(log2 e): feats pre-scaled so exp==exp2
#define SB (SQL2E / 8.0f)     // THETA_ALPHA
#define SC (SQL2E / 0.5f)     // THETA_BETA

#if __has_builtin(__builtin_amdgcn_exp2f)
#define EXP2(x) __builtin_amdgcn_exp2f(x)
#else
#define EXP2(x) exp2f(x)
#endif

// One-time: feats[i] = {fh,fw,fd,c0 | c1,c2,nn,0}; sm0 = softmax(u).
__global__ __launch_bounds__(256) void prep(
    const float* __restrict__ u, const float* __restrict__ rgb,
    float* __restrict__ feats, float* __restrict__ sm0)
{
    int i = blockIdx.x * 256 + threadIdx.x;
    int h = i >> 8, r = i & 255, w = r >> 4, d = r & 15;
    float fh = (float)(h + 1) * SB;
    float fw = (float)(w + 1) * SB;
    float fd = (float)(d + 1) * SB;
    float c0 = rgb[3 * i + 0] * SC;
    float c1 = rgb[3 * i + 1] * SC;
    float c2 = rgb[3 * i + 2] * SC;
    float nn = -0.5f * (fh * fh + fw * fw + fd * fd + c0 * c0 + c1 * c1 + c2 * c2);
    ((float4*)feats)[2 * i + 0] = make_float4(fh, fw, fd, c0);
    ((float4*)feats)[2 * i + 1] = make_float4(c1, c2, nn, 0.0f);

    float4 q = ((const float4*)u)[i];
    float m = fmaxf(fmaxf(q.x, q.y), fmaxf(q.z, q.w));
    float e0 = EXP2((q.x - m) * L2E), e1 = EXP2((q.y - m) * L2E);
    float e2 = EXP2((q.z - m) * L2E), e3 = EXP2((q.w - m) * L2E);
    float rs = 1.0f / (e0 + e1 + e2 + e3);
    ((float4*)sm0)[i] = make_float4(e0 * rs, e1 * rs, e2 * rs, e3 * rs);
}

// blocks [0,32): spatial conv D,W on sm -> tmp.  blocks [32, 32+GB): bilateral.
__global__ __launch_bounds__(256, 8) void fused(
    const float* __restrict__ sm,    // [N][4] softmax(q)
    const float* __restrict__ feats, // [N][8]
    float* __restrict__ part,        // [KS][N*4]
    float* __restrict__ tmp)         // [N][4] d,w-convolved sm
{
    __shared__ float lds[2048];      // conv: A[1024]|B[1024]; bilat: recs 64*12
    int tid = threadIdx.x;

    if (blockIdx.x >= CONVB) {
        // ---------------- bilateral N^2 ----------------
        int b = blockIdx.x - CONVB;
        int ib = b >> 7;                 // 16 i-tiles (512 rows each)
        int kc = b & (KS - 1);           // 128 j-chunks
        int i0 = ib * 512 + tid;         // rows: i0, i0+256
        int i1 = i0 + 256;
        int j0 = kc * JC;

        const float4* f4 = (const float4*)feats;
        const float4* s4 = (const float4*)sm;

        // stage JC=64 j-records {f0..f7 | s0..s3} as 3 float4s each (coalesced)
        float4* lrec = (float4*)lds;
        if (tid < 128) {
            float4 v = f4[2 * j0 + tid];
            lrec[(tid >> 1) * 3 + (tid & 1)] = v;
        } else if (tid < 192) {
            int jj = tid - 128;
            lrec[jj * 3 + 2] = s4[j0 + jj];
        }

        // i-side: 4 coalesced float4 loads, rows differ by delta only
        float4 A0 = f4[2 * i0], A1 = f4[2 * i0 + 1];
        float4 B0 = f4[2 * i1], B1 = f4[2 * i1 + 1];
        float dfh = B0.x - A0.x;         // = SB
        float dc0 = B0.w - A0.w, dc1 = B1.x - A1.x, dc2 = B1.y - A1.y;
        float dn  = B1.z - A1.z;
        __syncthreads();

        float a0 = 0, a1 = 0, a2 = 0, a3 = 0;
        float b0 = 0, b1 = 0, b2 = 0, b3 = 0;

        #pragma unroll 4
        for (int jj = 0; jj < JC; ++jj) {
            float4 r0 = lrec[jj * 3 + 0];
            float4 r1 = lrec[jj * 3 + 1];
            float4 s  = lrec[jj * 3 + 2];
            float g0 = A1.z + r1.z;
            g0 = fmaf(A0.x, r0.x, g0);
            g0 = fmaf(A0.y, r0.y, g0);
            g0 = fmaf(A0.z, r0.z, g0);
            g0 = fmaf(A0.w, r0.w, g0);
            g0 = fmaf(A1.x, r1.x, g0);
            g0 = fmaf(A1.y, r1.y, g0);
            float g1 = fmaf(dfh, r0.x, g0 + dn);
            g1 = fmaf(dc0, r0.w, g1);
            g1 = fmaf(dc1, r1.x, g1);
            g1 = fmaf(dc2, r1.y, g1);
            float w0 = EXP2(g0);
            float w1 = EXP2(g1);
            a0 = fmaf(w0, s.x, a0); a1 = fmaf(w0, s.y, a1);
            a2 = fmaf(w0, s.z, a2); a3 = fmaf(w0, s.w, a3);
            b0 = fmaf(w1, s.x, b0); b1 = fmaf(w1, s.y, b1);
            b2 = fmaf(w1, s.z, b2); b3 = fmaf(w1, s.w, b3);
        }

        float4* p = (float4*)(part + (size_t)kc * (NN * 4));
        p[i0] = make_float4(a0, a1, a2, a3);
        p[i1] = make_float4(b0, b1, b2, b3);
    } else {
        // ---------------- spatial conv D, conv W ----------------
        int h = blockIdx.x;
        int s = tid;                 // s = w*16 + d
        int i = h * 256 + s;

        float* A = lds;              // [256][4]
        float* B = lds + 1024;       // [256][4]
        *((float4*)(A + 4 * s)) = ((const float4*)sm)[i];
        __syncthreads();

        int w = s >> 4, d = s & 15;
        float t0 = 0, t1 = 0, t2 = 0, t3 = 0;
        #pragma unroll
        for (int dp = 0; dp < DDD; ++dp) {
            float dd = (float)(d - dp);
            float k = EXP2(-dd * dd * C18);
            const float4 v = *((const float4*)(A + 4 * (w * 16 + dp)));
            t0 = fmaf(k, v.x, t0); t1 = fmaf(k, v.y, t1);
            t2 = fmaf(k, v.z, t2); t3 = fmaf(k, v.w, t3);
        }
        *((float4*)(B + 4 * s)) = make_float4(t0, t1, t2, t3);
        __syncthreads();

        float u0 = 0, u1 = 0, u2 = 0, u3 = 0;
        #pragma unroll
        for (int wp = 0; wp < WW; ++wp) {
            float dw = (float)(w - wp);
            float k = EXP2(-dw * dw * C18);
            const float4 v = *((const float4*)(B + 4 * (wp * 16 + d)));
            u0 = fmaf(k, v.x, u0); u1 = fmaf(k, v.y, u1);
            u2 = fmaf(k, v.z, u2); u3 = fmaf(k, v.w, u3);
        }
        *((float4*)(tmp + 4 * i)) = make_float4(u0, u1, u2, u3);
    }
}

// 512 blocks x 256 thr. Block owns 64 idx (= 16 i x 4 c).
// Wave q sums part slices [q*32, q*32+32) + 8 hp of h-conv; LDS combine;
// threads 0..15: normalize + 4x4 matmuls + unary add -> qout, AND softmax -> smout.
__global__ __launch_bounds__(256) void reduce_finish(
    const float* __restrict__ part,  // [KS][N*4]
    const float* __restrict__ tmp,   // [N][4] d,w-convolved sm
    const float* __restrict__ u,
    const float* __restrict__ sk, const float* __restrict__ bk,
    const float* __restrict__ cm,
    float* __restrict__ qout,
    float* __restrict__ smout)       // softmax(qout) for the next iteration
{
    int tid = threadIdx.x;
    int q = tid >> 6;                // wave 0..3
    int lane = tid & 63;
    int idx = blockIdx.x * 64 + lane;

    float bl = 0.0f;
    #pragma unroll
    for (int k = 0; k < KS / 4; ++k)
        bl += part[(size_t)(q * (KS / 4) + k) * (NN * 4) + idx];

    int i = idx >> 2;
    int h = i >> 8;
    int scid = idx & 1023;
    float sp = 0.0f;
    #pragma unroll
    for (int k = 0; k < 8; ++k) {
        int hp = q * 8 + k;
        float dh = (float)(h - hp);
        float kk = EXP2(-dh * dh * C18);
        sp = fmaf(kk, tmp[hp * 1024 + scid], sp);
    }

    __shared__ float Lb[4][64];
    __shared__ float Ls[4][64];
    Lb[q][lane] = bl;
    Ls[q][lane] = sp;
    __syncthreads();

    if (tid < 16) {
        float b4[4], s4[4];
        #pragma unroll
        for (int c = 0; c < 4; ++c) {
            int l = tid * 4 + c;
            b4[c] = Lb[0][l] + Lb[1][l] + Lb[2][l] + Lb[3][l];
            s4[c] = Ls[0][l] + Ls[1][l] + Ls[2][l] + Ls[3][l];
        }
        float rb = 1.0f / (b4[0] + b4[1] + b4[2] + b4[3]);
        float rs = 1.0f / (s4[0] + s4[1] + s4[2] + s4[3]);
        float bo[4], so[4];
        #pragma unroll
        for (int c = 0; c < 4; ++c) { bo[c] = b4[c] * rb; so[c] = s4[c] * rs; }
        float msg[4];
        #pragma unroll
        for (int c = 0; c < 4; ++c) {
            float m = 0.0f;
            #pragma unroll
            for (int d = 0; d < 4; ++d)
                m += sk[c * 4 + d] * so[d] + bk[c * 4 + d] * bo[d];
            msg[c] = m;
        }
        int ig = blockIdx.x * 16 + tid;
        float qv[4];
        #pragma unroll
        for (int c = 0; c < 4; ++c) {
            float pw = 0.0f;
            #pragma unroll
            for (int d = 0; d < 4; ++d) pw += cm[c * 4 + d] * msg[d];
            qv[c] = u[4 * ig + c] + pw;
        }
        *((float4*)(qout + 4 * ig)) = make_float4(qv[0], qv[1], qv[2], qv[3]);

        float mm = fmaxf(fmaxf(qv[0], qv[1]), fmaxf(qv[2], qv[3]));
        float e0 = EXP2((qv[0] - mm) * L2E), e1 = EXP2((qv[1] - mm) * L2E);
        float e2 = EXP2((qv[2] - mm) * L2E), e3 = EXP2((qv[3] - mm) * L2E);
        float er = 1.0f / (e0 + e1 + e2 + e3);
        *((float4*)(smout + 4 * ig)) = make_float4(e0 * er, e1 * er, e2 * er, e3 * er);
    }
}

extern "C" void kernel_launch(void* const* d_in, const int* in_sizes, int n_in,
                              void* d_out, int out_size, void* d_ws, size_t ws_size,
                              hipStream_t stream)
{
    const float* u   = (const float*)d_in[0];
    const float* rgb = (const float*)d_in[1];
    const float* sk  = (const float*)d_in[2];
    const float* bk  = (const float*)d_in[3];
    const float* cm  = (const float*)d_in[4];
    float* out = (float*)d_out;

    // ws: part[KS][N*4] (16MB) | feats[N*8] | tmp[N*4] | smA | smB | qbuf | smDead
    float* part   = (float*)d_ws;
    float* feats  = part  + (size_t)KS * NN * 4;
    float* tmpP   = feats + (size_t)NN * 8;
    float* smA    = tmpP  + (size_t)NN * 4;
    float* smB    = smA   + (size_t)NN * 4;
    float* qbuf   = smB   + (size_t)NN * 4;
    float* smDead = qbuf  + (size_t)NN * 4;

    dim3 blk(256);
    dim3 gP(NN / 256);           // 32
    dim3 gF(CONVB + GB);         // 32 + 2048
    dim3 gR(NN * 4 / 64);        // 512

    prep<<<gP, blk, 0, stream>>>(u, rgb, feats, smA);
    // iteration 1 (q = u)
    fused<<<gF, blk, 0, stream>>>(smA, feats, part, tmpP);
    reduce_finish<<<gR, blk, 0, stream>>>(part, tmpP, u, sk, bk, cm, qbuf, smB);
    // iteration 2
    fused<<<gF, blk, 0, stream>>>(smB, feats, part, tmpP);
    reduce_finish<<<gR, blk, 0, stream>>>(part, tmpP, u, sk, bk, cm, out, smDead);
}